// Round 7
// baseline (3067.271 us; speedup 1.0000x reference)
//
#include <hip/hip_runtime.h>
#include <hip/hip_fp16.h>

#define NEG_SLOPE 0.2f
#define BKT_SHIFT 8
#define BKT_NODES 256
#define BKT_CAP 10240
#define SRC_SHIFT 18
#define SRC_MASK 0x3FFFF
#define CHUNK 8192
#define NBMAX 512

typedef _Float16 half8 __attribute__((ext_vector_type(8)));
typedef float float4v __attribute__((ext_vector_type(4)));

__device__ __forceinline__ int wave_iscan(int v, int lane) {
#pragma unroll
    for (int off = 1; off < 64; off <<= 1) {
        int u = __shfl_up(v, off);
        if (lane >= off) v += u;
    }
    return v;
}

// ---------------- Kernel: node prep layer 1 ----------------
__global__ void k_node1(const float* __restrict__ x, const int* __restrict__ type_ids,
                        const float* __restrict__ type_emb, const float* __restrict__ W1,
                        const float* __restrict__ a_src1, const float* __restrict__ a_dst1,
                        __half2* __restrict__ h1h, float* __restrict__ als1, float* __restrict__ ald1,
                        int N)
{
    int node = blockIdx.x * 4 + (threadIdx.x >> 6);
    int j = threadIdx.x & 63;
    if (node >= N) return;

    float xin[21];
#pragma unroll
    for (int k = 0; k < 5; k++) xin[k] = x[node * 5 + k];
    int t = type_ids[node];
#pragma unroll
    for (int k = 0; k < 16; k++) xin[5 + k] = type_emb[t * 16 + k];

    float h = 0.f;
#pragma unroll
    for (int k = 0; k < 21; k++) h += xin[k] * W1[k * 64 + j];

    float hn = __shfl_xor(h, 1);
    if ((j & 1) == 0)
        h1h[node * 32 + (j >> 1)] = __floats2half2_rn(h, hn);

    int head = j >> 5, lane = j & 31;
    float ps = h * a_src1[head * 32 + lane];
    float pd = h * a_dst1[head * 32 + lane];
#pragma unroll
    for (int m = 16; m >= 1; m >>= 1) { ps += __shfl_xor(ps, m); pd += __shfl_xor(pd, m); }
    if (lane == 0) { als1[node * 2 + head] = ps; ald1[node * 2 + head] = pd; }
}

// ---------------- Bucket build: 512-thread register-staged bucket append ----------------
__global__ __launch_bounds__(512) void k_bucketA(
        const int* __restrict__ ei, unsigned int* __restrict__ pk,
        int* __restrict__ bcnt, int E, int NBKT)
{
    __shared__ unsigned int stage[CHUNK];
    __shared__ unsigned short stageB[CHUNK];
    __shared__ int cnt[NBMAX];
    __shared__ int excl[NBMAX];
    __shared__ int curp[NBMAX];
    __shared__ int gbase[NBMAX];
    __shared__ int wpart[8];

    int t = threadIdx.x;
    int lane = t & 63, wv = t >> 6;
    int e0 = blockIdx.x * CHUNK;
    bool vec4 = ((E & 3) == 0);

    cnt[t] = 0;
    __syncthreads();

    int4 s4[4], d4[4];
    bool val[4];

    if (vec4) {
#pragma unroll
        for (int it = 0; it < 4; it++) {
            int e = e0 + it * 2048 + t * 4;
            val[it] = (e < E);
            if (val[it]) {
                s4[it] = *(const int4*)(ei + e);
                d4[it] = *(const int4*)(ei + (size_t)E + e);
                atomicAdd(&cnt[d4[it].x >> BKT_SHIFT], 1);
                atomicAdd(&cnt[d4[it].y >> BKT_SHIFT], 1);
                atomicAdd(&cnt[d4[it].z >> BKT_SHIFT], 1);
                atomicAdd(&cnt[d4[it].w >> BKT_SHIFT], 1);
            }
        }
    } else {
        for (int i = t; i < CHUNK; i += 512) {
            int e = e0 + i;
            if (e >= E) break;
            atomicAdd(&cnt[ei[E + e] >> BKT_SHIFT], 1);
        }
    }
    __syncthreads();
    int myc = cnt[t];
    int incl = wave_iscan(myc, lane);
    if (lane == 63) wpart[wv] = incl;
    __syncthreads();
#pragma unroll
    for (int k = 0; k < 8; k++)
        if (k < wv) incl += wpart[k];
    {
        int ex = incl - myc;
        excl[t] = ex;
        curp[t] = ex;
        if (t < NBKT)
            gbase[t] = (myc > 0) ? atomicAdd(&bcnt[t], myc) : 0;
    }
    __syncthreads();
    if (vec4) {
#pragma unroll
        for (int it = 0; it < 4; it++) {
            if (!val[it]) continue;
            int ss[4] = {s4[it].x, s4[it].y, s4[it].z, s4[it].w};
            int dd[4] = {d4[it].x, d4[it].y, d4[it].z, d4[it].w};
#pragma unroll
            for (int k = 0; k < 4; k++) {
                int b = dd[k] >> BKT_SHIFT;
                int p = atomicAdd(&curp[b], 1);
                stage[p] = (unsigned)ss[k] | ((unsigned)(dd[k] & (BKT_NODES - 1)) << SRC_SHIFT);
                stageB[p] = (unsigned short)b;
            }
        }
    } else {
        for (int i = t; i < CHUNK; i += 512) {
            int e = e0 + i;
            if (e >= E) break;
            int s = ei[e], d = ei[E + e];
            int b = d >> BKT_SHIFT;
            int p = atomicAdd(&curp[b], 1);
            stage[p] = (unsigned)s | ((unsigned)(d & (BKT_NODES - 1)) << SRC_SHIFT);
            stageB[p] = (unsigned short)b;
        }
    }
    __syncthreads();
    int total = E - e0; if (total > CHUNK) total = CHUNK;
    for (int i = t; i < total; i += 512) {
        int b = stageB[i];
        int idx = gbase[b] + (i - excl[b]);
        if (idx < BKT_CAP) pk[(size_t)b * BKT_CAP + idx] = stage[i];
    }
}

// ---------------- Gather layer 1, bucket-direct: LDS accumulate ----------------
__global__ __launch_bounds__(512) void k_gb1(
        const unsigned int* __restrict__ pk, const int* __restrict__ bcnt,
        const float4* __restrict__ h4, const float* __restrict__ als1,
        const float* __restrict__ ald1, const float* __restrict__ b1,
        float4* __restrict__ h2h4, int N)
{
    __shared__ float acc[BKT_NODES][65];
    __shared__ float wsum[BKT_NODES][2];
    __shared__ float aldl[BKT_NODES][2];

    int b = blockIdx.x, t = threadIdx.x;
    int nbase = b << BKT_SHIFT;
    int nn = min(BKT_NODES, N - nbase);
    int nb = min(bcnt[b], BKT_CAP);

    for (int idx = t; idx < BKT_NODES * 65; idx += 512) ((float*)acc)[idx] = 0.f;
    if (t < BKT_NODES) {
        wsum[t][0] = 0.f; wsum[t][1] = 0.f;
        if (t < nn) {
            int n = nbase + t;
            aldl[t][0] = ald1[n * 2 + 0];
            aldl[t][1] = ald1[n * 2 + 1];
        }
    }
    __syncthreads();

    const unsigned int* mypk = pk + (size_t)b * BKT_CAP;
    int l = t & 63;
    int i = l & 7, grpbase = l & 56;

    for (int e0 = 0; e0 < nb; e0 += 512) {
        int e = e0 + t;
        bool valid = e < nb;
        unsigned entry = mypk[valid ? e : 0];
        float w0 = 0.f, w1 = 0.f;
        if (valid) {
            int s = entry & SRC_MASK;
            int dl = entry >> SRC_SHIFT;
            float2 al = *(const float2*)(als1 + (size_t)s * 2);
            float lg0 = al.x + aldl[dl][0]; lg0 = (lg0 >= 0.f) ? lg0 : NEG_SLOPE * lg0;
            float lg1 = al.y + aldl[dl][1]; lg1 = (lg1 >= 0.f) ? lg1 : NEG_SLOPE * lg1;
            w0 = __expf(lg0);
            w1 = __expf(lg1);
            atomicAdd(&wsum[dl][0], w0);
            atomicAdd(&wsum[dl][1], w1);
        }
        __half2 wp = __floats2half2_rn(w0, w1);
        unsigned wpi = *(unsigned*)&wp;

#pragma unroll
        for (int r = 0; r < 8; r++) {
            int srcl = grpbase + r;
            unsigned ent = __shfl(entry, srcl);
            unsigned wri = __shfl(wpi, srcl);
            int sr = ent & SRC_MASK;
            int dr = ent >> SRC_SHIFT;
            __half2 wh = *(__half2*)&wri;
            float w = (i < 4) ? __low2float(wh) : __high2float(wh);
            float4 rv = h4[(size_t)sr * 8 + i];
            const __half* hp = (const __half*)&rv;
            float* ap = &acc[dr][i * 8];
#pragma unroll
            for (int k = 0; k < 8; k++)
                atomicAdd(&ap[k], w * __half2float(hp[k]));
        }
    }
    __syncthreads();

    // finish: self loop + normalize + bias + relu, 4 passes x 64 nodes x 8 owners
    for (int p = 0; p < 4; p++) {
        int d = p * 64 + (t >> 3);
        if (d >= nn) continue;
        int n = nbase + d;
        float2 al = *(const float2*)(als1 + (size_t)n * 2);
        float lg0 = al.x + aldl[d][0]; lg0 = (lg0 >= 0.f) ? lg0 : NEG_SLOPE * lg0;
        float lg1 = al.y + aldl[d][1]; lg1 = (lg1 >= 0.f) ? lg1 : NEG_SLOPE * lg1;
        float w0s = __expf(lg0), w1s = __expf(lg1);
        float ws = (i < 4) ? w0s : w1s;
        float inv = 1.f / (((i < 4) ? wsum[d][0] : wsum[d][1]) + ws + 1e-16f);
        float4 rv = h4[(size_t)n * 8 + i];
        const __half* hp = (const __half*)&rv;
        union { float4 f4; __half2 h2[4]; } u;
#pragma unroll
        for (int q = 0; q < 4; q++) {
            float v0 = (acc[d][i * 8 + 2 * q]     + ws * __half2float(hp[2 * q]))     * inv + b1[i * 8 + 2 * q];
            float v1 = (acc[d][i * 8 + 2 * q + 1] + ws * __half2float(hp[2 * q + 1])) * inv + b1[i * 8 + 2 * q + 1];
            u.h2[q] = __floats2half2_rn(fmaxf(v0, 0.f), fmaxf(v1, 0.f));
        }
        h2h4[(size_t)n * 8 + i] = u.f4;
    }
}

// ---------------- MFMA projection: h3 = h2 @ W2 (fp16 in, fp32 acc) + logits ----------------
__global__ __launch_bounds__(256) void k_node2m(
        const _Float16* __restrict__ h2h, const float* __restrict__ W2,
        const float* __restrict__ a_src2, const float* __restrict__ a_dst2,
        _Float16* __restrict__ h3h, float* __restrict__ als2, float* __restrict__ ald2, int N)
{
    __shared__ _Float16 w2t[64][72];
    __shared__ float h3t[4][16][65];
    int t = threadIdx.x;
    for (int e = t; e < 4096; e += 256) {
        int k = e >> 6, n = e & 63;
        w2t[n][k] = (_Float16)W2[e];
    }
    __syncthreads();

    int w = t >> 6, l = t & 63;
    int l15 = l & 15, quad = l >> 4;
    int nodebase = blockIdx.x * 64 + w * 16;

    int arow = nodebase + l15;
    if (arow >= N) arow = N - 1;
    const half8* ap = (const half8*)(h2h + (size_t)arow * 64 + quad * 8);
    half8 a0 = ap[0];
    half8 a1 = ap[4];
    float4v accs[4];
#pragma unroll
    for (int nt = 0; nt < 4; nt++) {
        half8 b0 = *(const half8*)(&w2t[nt * 16 + l15][quad * 8]);
        half8 b1 = *(const half8*)(&w2t[nt * 16 + l15][32 + quad * 8]);
        float4v c = {0.f, 0.f, 0.f, 0.f};
        c = __builtin_amdgcn_mfma_f32_16x16x32_f16(a0, b0, c, 0, 0, 0);
        c = __builtin_amdgcn_mfma_f32_16x16x32_f16(a1, b1, c, 0, 0, 0);
        accs[nt] = c;
    }
#pragma unroll
    for (int nt = 0; nt < 4; nt++)
#pragma unroll
        for (int r = 0; r < 4; r++)
            h3t[w][quad * 4 + r][nt * 16 + l15] = accs[nt][r];
    __syncthreads();

    int m = l >> 2, part = l & 3;
    int g = blockIdx.x * 64 + w * 16 + m;
    float ps = 0.f, pd = 0.f;
    union { float4 f4[2]; _Float16 h[16]; } u;
#pragma unroll
    for (int c = 0; c < 16; c++) {
        float v = h3t[w][m][part * 16 + c];
        ps += v * a_src2[part * 16 + c];
        pd += v * a_dst2[part * 16 + c];
        u.h[c] = (_Float16)v;
    }
    if (g < N) {
        float4* dst = (float4*)(h3h + (size_t)g * 64) + part * 2;
        dst[0] = u.f4[0];
        dst[1] = u.f4[1];
    }
    ps += __shfl_xor(ps, 1); ps += __shfl_xor(ps, 2);
    pd += __shfl_xor(pd, 1); pd += __shfl_xor(pd, 2);
    if (part == 0 && g < N) { als2[g] = ps; ald2[g] = pd; }
}

// ---------------- Gather layer 2, bucket-direct + LayerNorm ----------------
__global__ __launch_bounds__(512) void k_gb2(
        const unsigned int* __restrict__ pk, const int* __restrict__ bcnt,
        const float4* __restrict__ h4, const float* __restrict__ als2,
        const float* __restrict__ ald2, const float* __restrict__ b2,
        const float* __restrict__ gamma, const float* __restrict__ beta,
        float* __restrict__ out, int N)
{
    __shared__ float acc[BKT_NODES][65];
    __shared__ float wsum[BKT_NODES];
    __shared__ float aldl[BKT_NODES];

    int b = blockIdx.x, t = threadIdx.x;
    int nbase = b << BKT_SHIFT;
    int nn = min(BKT_NODES, N - nbase);
    int nb = min(bcnt[b], BKT_CAP);

    for (int idx = t; idx < BKT_NODES * 65; idx += 512) ((float*)acc)[idx] = 0.f;
    if (t < BKT_NODES) {
        wsum[t] = 0.f;
        if (t < nn) aldl[t] = ald2[nbase + t];
    }
    __syncthreads();

    const unsigned int* mypk = pk + (size_t)b * BKT_CAP;
    int l = t & 63;
    int i = l & 7, grpbase = l & 56;

    for (int e0 = 0; e0 < nb; e0 += 512) {
        int e = e0 + t;
        bool valid = e < nb;
        unsigned entry = mypk[valid ? e : 0];
        float w = 0.f;
        if (valid) {
            int s = entry & SRC_MASK;
            int dl = entry >> SRC_SHIFT;
            float lg = als2[s] + aldl[dl];
            lg = (lg >= 0.f) ? lg : NEG_SLOPE * lg;
            w = __expf(lg);
            atomicAdd(&wsum[dl], w);
        }

#pragma unroll
        for (int r = 0; r < 8; r++) {
            int srcl = grpbase + r;
            unsigned ent = __shfl(entry, srcl);
            float wr = __shfl(w, srcl);
            int sr = ent & SRC_MASK;
            int dr = ent >> SRC_SHIFT;
            float4 rv = h4[(size_t)sr * 8 + i];
            const __half* hp = (const __half*)&rv;
            float* ap = &acc[dr][i * 8];
#pragma unroll
            for (int k = 0; k < 8; k++)
                atomicAdd(&ap[k], wr * __half2float(hp[k]));
        }
    }
    __syncthreads();

    // finish: self loop + normalize + bias + LN, 4 passes x 64 nodes x 8 owners
    for (int p = 0; p < 4; p++) {
        int d = p * 64 + (t >> 3);
        if (d >= nn) continue;
        int n = nbase + d;
        float lg = als2[n] + aldl[d];
        lg = (lg >= 0.f) ? lg : NEG_SLOPE * lg;
        float ws = __expf(lg);
        float inv = 1.f / (wsum[d] + ws + 1e-16f);
        float4 rv = h4[(size_t)n * 8 + i];
        const __half* hp = (const __half*)&rv;
        float o[8];
        float s = 0.f;
#pragma unroll
        for (int k = 0; k < 8; k++) {
            o[k] = (acc[d][i * 8 + k] + ws * __half2float(hp[k])) * inv + b2[i * 8 + k];
            s += o[k];
        }
        s += __shfl_xor(s, 1); s += __shfl_xor(s, 2); s += __shfl_xor(s, 4);
        float mu = s * (1.f / 64.f);
        float v = 0.f;
#pragma unroll
        for (int k = 0; k < 8; k++) { float dd = o[k] - mu; v += dd * dd; }
        v += __shfl_xor(v, 1); v += __shfl_xor(v, 2); v += __shfl_xor(v, 4);
        v *= (1.f / 64.f);
        float rstd = rsqrtf(v + 1e-5f);
        float res[8];
#pragma unroll
        for (int k = 0; k < 8; k++)
            res[k] = (o[k] - mu) * rstd * gamma[i * 8 + k] + beta[i * 8 + k];
        float4* op = (float4*)(out + (size_t)n * 64 + i * 8);
        op[0] = make_float4(res[0], res[1], res[2], res[3]);
        op[1] = make_float4(res[4], res[5], res[6], res[7]);
    }
}

extern "C" void kernel_launch(void* const* d_in, const int* in_sizes, int n_in,
                              void* d_out, int out_size, void* d_ws, size_t ws_size,
                              hipStream_t stream) {
    const float* x        = (const float*)d_in[0];
    const int*   ei       = (const int*)  d_in[1];
    const int*   type_ids = (const int*)  d_in[2];
    const float* type_emb = (const float*)d_in[3];
    const float* W1       = (const float*)d_in[4];
    const float* a_src1   = (const float*)d_in[5];
    const float* a_dst1   = (const float*)d_in[6];
    const float* b1       = (const float*)d_in[7];
    const float* W2       = (const float*)d_in[8];
    const float* a_src2   = (const float*)d_in[9];
    const float* a_dst2   = (const float*)d_in[10];
    const float* b2       = (const float*)d_in[11];
    const float* gamma    = (const float*)d_in[12];
    const float* beta     = (const float*)d_in[13];

    int N = in_sizes[0] / 5;
    int E = in_sizes[1] / 2;
    int NBKT = (N + BKT_NODES - 1) >> BKT_SHIFT;

    // Workspace: pk lives through both gathers now (no overlay).
    char* base = (char*)d_ws;
    size_t off = 0;
    auto carve = [&](size_t bytes) { void* p = base + off; off += (bytes + 255) & ~(size_t)255; return p; };
    __half2* h1h = (__half2*)carve((size_t)N * 64 * sizeof(__half));
    unsigned int* pk = (unsigned int*)carve((size_t)NBKT * BKT_CAP * sizeof(unsigned int));
    _Float16* h2h = (_Float16*)carve((size_t)N * 64 * sizeof(__half));
    _Float16* h3h = (_Float16*)carve((size_t)N * 64 * sizeof(__half));
    float* als1  = (float*)carve((size_t)N * 2 * sizeof(float));
    float* ald1  = (float*)carve((size_t)N * 2 * sizeof(float));
    float* als2  = (float*)carve((size_t)N * sizeof(float));
    float* ald2  = (float*)carve((size_t)N * sizeof(float));
    int*   bcnt  = (int*)carve(1024 * sizeof(int));

    dim3 tb(256);
    dim3 tb512(512);

    k_node1<<<dim3((N + 3) / 4), tb, 0, stream>>>(x, type_ids, type_emb, W1, a_src1, a_dst1,
                                                  h1h, als1, ald1, N);

    hipMemsetAsync(bcnt, 0, NBKT * sizeof(int), stream);
    k_bucketA<<<dim3((E + CHUNK - 1) / CHUNK), tb512, 0, stream>>>(ei, pk, bcnt, E, NBKT);

    k_gb1<<<dim3(NBKT), tb512, 0, stream>>>(pk, bcnt, (const float4*)h1h, als1, ald1, b1,
                                            (float4*)h2h, N);
    k_node2m<<<dim3((N + 63) / 64), tb, 0, stream>>>(h2h, W2, a_src2, a_dst2,
                                                     h3h, als2, ald2, N);
    k_gb2<<<dim3(NBKT), tb512, 0, stream>>>(pk, bcnt, (const float4*)h3h, als2, ald2, b2,
                                            gamma, beta, (float*)d_out, N);
}

// Round 8
// 301.006 us; speedup vs baseline: 10.1901x; 10.1901x over previous
//
#include <hip/hip_runtime.h>
#include <hip/hip_fp16.h>

#define NEG_SLOPE 0.2f
#define BKT_SHIFT 8
#define BKT_NODES 256
#define BKT_CAP 10240
#define SRC_SHIFT 18
#define SRC_MASK 0x3FFFF
#define CHUNK 8192
#define NBMAX 512

typedef _Float16 half8 __attribute__((ext_vector_type(8)));
typedef float float4v __attribute__((ext_vector_type(4)));

__device__ __forceinline__ int wave_iscan(int v, int lane) {
#pragma unroll
    for (int off = 1; off < 64; off <<= 1) {
        int u = __shfl_up(v, off);
        if (lane >= off) v += u;
    }
    return v;
}

// ---------------- Kernel: node prep layer 1 (+ bcnt zeroing) ----------------
__global__ void k_node1(const float* __restrict__ x, const int* __restrict__ type_ids,
                        const float* __restrict__ type_emb, const float* __restrict__ W1,
                        const float* __restrict__ a_src1, const float* __restrict__ a_dst1,
                        __half2* __restrict__ h1h, float* __restrict__ als1, float* __restrict__ ald1,
                        int* __restrict__ bcnt, int N)
{
    if (blockIdx.x == 0) {
        for (int z = threadIdx.x; z < 1024; z += 256) bcnt[z] = 0;
    }
    int node = blockIdx.x * 4 + (threadIdx.x >> 6);
    int j = threadIdx.x & 63;
    if (node >= N) return;

    float xin[21];
#pragma unroll
    for (int k = 0; k < 5; k++) xin[k] = x[node * 5 + k];
    int t = type_ids[node];
#pragma unroll
    for (int k = 0; k < 16; k++) xin[5 + k] = type_emb[t * 16 + k];

    float h = 0.f;
#pragma unroll
    for (int k = 0; k < 21; k++) h += xin[k] * W1[k * 64 + j];

    float hn = __shfl_xor(h, 1);
    if ((j & 1) == 0)
        h1h[node * 32 + (j >> 1)] = __floats2half2_rn(h, hn);

    int head = j >> 5, lane = j & 31;
    float ps = h * a_src1[head * 32 + lane];
    float pd = h * a_dst1[head * 32 + lane];
#pragma unroll
    for (int m = 16; m >= 1; m >>= 1) { ps += __shfl_xor(ps, m); pd += __shfl_xor(pd, m); }
    if (lane == 0) { als1[node * 2 + head] = ps; ald1[node * 2 + head] = pd; }
}

// ---------------- CSR build, phase A: 512-thread register-staged bucket append ----------------
__global__ __launch_bounds__(512) void k_bucketA(
        const int* __restrict__ ei, unsigned int* __restrict__ pk,
        int* __restrict__ bcnt, int E, int NBKT)
{
    __shared__ unsigned int stage[CHUNK];
    __shared__ unsigned short stageB[CHUNK];
    __shared__ int cnt[NBMAX];
    __shared__ int excl[NBMAX];
    __shared__ int curp[NBMAX];
    __shared__ int gbase[NBMAX];
    __shared__ int wpart[8];

    int t = threadIdx.x;
    int lane = t & 63, wv = t >> 6;
    int e0 = blockIdx.x * CHUNK;
    bool vec4 = ((E & 3) == 0);

    cnt[t] = 0;
    __syncthreads();

    int4 s4[4], d4[4];
    bool val[4];

    if (vec4) {
#pragma unroll
        for (int it = 0; it < 4; it++) {
            int e = e0 + it * 2048 + t * 4;
            val[it] = (e < E);
            if (val[it]) {
                s4[it] = *(const int4*)(ei + e);
                d4[it] = *(const int4*)(ei + (size_t)E + e);
                atomicAdd(&cnt[d4[it].x >> BKT_SHIFT], 1);
                atomicAdd(&cnt[d4[it].y >> BKT_SHIFT], 1);
                atomicAdd(&cnt[d4[it].z >> BKT_SHIFT], 1);
                atomicAdd(&cnt[d4[it].w >> BKT_SHIFT], 1);
            }
        }
    } else {
        for (int i = t; i < CHUNK; i += 512) {
            int e = e0 + i;
            if (e >= E) break;
            atomicAdd(&cnt[ei[E + e] >> BKT_SHIFT], 1);
        }
    }
    __syncthreads();
    int myc = cnt[t];
    int incl = wave_iscan(myc, lane);
    if (lane == 63) wpart[wv] = incl;
    __syncthreads();
#pragma unroll
    for (int k = 0; k < 8; k++)
        if (k < wv) incl += wpart[k];
    {
        int ex = incl - myc;
        excl[t] = ex;
        curp[t] = ex;
        if (t < NBKT)
            gbase[t] = (myc > 0) ? atomicAdd(&bcnt[t], myc) : 0;
    }
    __syncthreads();
    if (vec4) {
#pragma unroll
        for (int it = 0; it < 4; it++) {
            if (!val[it]) continue;
            int ss[4] = {s4[it].x, s4[it].y, s4[it].z, s4[it].w};
            int dd[4] = {d4[it].x, d4[it].y, d4[it].z, d4[it].w};
#pragma unroll
            for (int k = 0; k < 4; k++) {
                int b = dd[k] >> BKT_SHIFT;
                int p = atomicAdd(&curp[b], 1);
                stage[p] = (unsigned)ss[k] | ((unsigned)(dd[k] & (BKT_NODES - 1)) << SRC_SHIFT);
                stageB[p] = (unsigned short)b;
            }
        }
    } else {
        for (int i = t; i < CHUNK; i += 512) {
            int e = e0 + i;
            if (e >= E) break;
            int s = ei[e], d = ei[E + e];
            int b = d >> BKT_SHIFT;
            int p = atomicAdd(&curp[b], 1);
            stage[p] = (unsigned)s | ((unsigned)(d & (BKT_NODES - 1)) << SRC_SHIFT);
            stageB[p] = (unsigned short)b;
        }
    }
    __syncthreads();
    int total = E - e0; if (total > CHUNK) total = CHUNK;
    for (int i = t; i < total; i += 512) {
        int b = stageB[i];
        int idx = gbase[b] + (i - excl[b]);
        if (idx < BKT_CAP) pk[(size_t)b * BKT_CAP + idx] = stage[i];
    }
}

// ---------------- CSR build, phase B: streaming per-bucket counting sort (inline base) ----------------
__global__ __launch_bounds__(512) void k_build(
        const unsigned int* __restrict__ pk, const int* __restrict__ bcnt,
        int* __restrict__ rs, int* __restrict__ cur,
        int* __restrict__ ssrc, int N)
{
    __shared__ int cnt[BKT_NODES];
    __shared__ int cursor[BKT_NODES];
    __shared__ int red[512];
    __shared__ int wpart[4];
    int b = blockIdx.x;
    int t = threadIdx.x;
    int lane = t & 63, wv = t >> 6;
    int nb = min(bcnt[b], BKT_CAP);

    int part = 0;
    for (int i = t; i < b; i += 512) part += min(bcnt[i], BKT_CAP);
    red[t] = part;
    if (t < BKT_NODES) cnt[t] = 0;
    __syncthreads();
    for (int off = 256; off; off >>= 1) {
        if (t < off) red[t] += red[t + off];
        __syncthreads();
    }
    int bs = red[0];

    const unsigned int* mypk = pk + (size_t)b * BKT_CAP;
    int nb4 = nb & ~3;
    for (int e = t * 4; e < nb4; e += 2048) {
        uint4 v = *(const uint4*)(mypk + e);
        atomicAdd(&cnt[v.x >> SRC_SHIFT], 1);
        atomicAdd(&cnt[v.y >> SRC_SHIFT], 1);
        atomicAdd(&cnt[v.z >> SRC_SHIFT], 1);
        atomicAdd(&cnt[v.w >> SRC_SHIFT], 1);
    }
    for (int e = nb4 + t; e < nb; e += 512) {
        atomicAdd(&cnt[mypk[e] >> SRC_SHIFT], 1);
    }
    __syncthreads();
    if (t < BKT_NODES) {
        int myc = cnt[t];
        int incl = wave_iscan(myc, lane);
        if (lane == 63) wpart[wv] = incl;
        __syncthreads();
#pragma unroll
        for (int k = 0; k < 4; k++)
            if (k < wv) incl += wpart[k];
        int ex = incl - myc;
        cursor[t] = ex;
        int node = (b << BKT_SHIFT) + t;
        if (node < N) { rs[node] = bs + ex; cur[node] = bs + ex + myc; }
    } else {
        __syncthreads();
    }
    __syncthreads();
    for (int e = t; e < nb; e += 512) {
        unsigned int w = mypk[e];
        int p = atomicAdd(&cursor[w >> SRC_SHIFT], 1);
        ssrc[bs + p] = (int)(w & SRC_MASK);
    }
}

// ---------------- Gather layer 1 + fused h2@W2 MFMA projection ----------------
__global__ __launch_bounds__(256) void k_gather1m(
        const int* __restrict__ rs, const int* __restrict__ cur,
        const int* __restrict__ ssrc, const float4* __restrict__ h4,
        const float* __restrict__ als1, const float* __restrict__ ald1,
        const float* __restrict__ b1, const float* __restrict__ W2,
        const float* __restrict__ a_src2, const float* __restrict__ a_dst2,
        _Float16* __restrict__ h3h, float* __restrict__ als2,
        float* __restrict__ ald2, int N)
{
    __shared__ _Float16 w2t[64][72];
    __shared__ float4 h2t[128];      // 16 nodes x 64 ch fp16
    __shared__ float h3t[16][65];

    int t = threadIdx.x;
    // stage W2 (sync deferred to the pre-MFMA barrier)
    for (int e = t; e < 4096; e += 256) {
        int kk = e >> 6, nn = e & 63;
        w2t[nn][kk] = (_Float16)W2[e];
    }

    int l = t & 63;
    int q = l & 15;          // lane within node group
    int i = q & 7;           // channel octet owner
    int hlf = q >> 3;        // slot-half
    int grpbase = l & 48;
    int head = i >> 2;
    int nl = t >> 4;         // local node 0..15

    int node = blockIdx.x * 16 + nl;
    bool live = node < N;
    int node_c = live ? node : (N - 1);

    int beg = rs[node_c];
    int cnt = live ? (cur[node_c] - beg) : 0;

    float ad0 = ald1[node_c * 2 + 0];
    float ad1 = ald1[node_c * 2 + 1];
    float ad = head ? ad1 : ad0;

    int mc = cnt;
    mc = max(mc, __shfl_xor(mc, 16));
    mc = max(mc, __shfl_xor(mc, 32));

    float acc[8];
#pragma unroll
    for (int k = 0; k < 8; k++) acc[k] = 0.f;
    float wsum = 0.f;

    for (int bb = 0; bb < mc; bb += 16) {
        int slot = bb + q;
        bool valid = slot < cnt;
        int idx = valid ? (beg + slot) : 0;
        int s = ssrc[idx];
        if (!valid) s = node_c;
        float2 al = *(const float2*)(als1 + (size_t)s * 2);
        float lg0 = al.x + ad0; lg0 = (lg0 >= 0.f) ? lg0 : NEG_SLOPE * lg0;
        float lg1 = al.y + ad1; lg1 = (lg1 >= 0.f) ? lg1 : NEG_SLOPE * lg1;
        float w0 = valid ? __expf(lg0) : 0.f;
        float w1 = valid ? __expf(lg1) : 0.f;
        __half2 wp = __floats2half2_rn(w0, w1);
        unsigned wpi = *(unsigned*)&wp;

#pragma unroll
        for (int r = 0; r < 8; r++) {
            int srcl = grpbase + hlf * 8 + r;
            int sr = __shfl(s, srcl);
            unsigned wri = __shfl(wpi, srcl);
            __half2 wh = *(__half2*)&wri;
            float w = head ? __high2float(wh) : __low2float(wh);
            float4 rv = h4[(size_t)sr * 8 + i];
            const __half* hp = (const __half*)&rv;
#pragma unroll
            for (int k = 0; k < 8; k++)
                acc[k] = fmaf(w, __half2float(hp[k]), acc[k]);
            wsum += w;
        }
    }

#pragma unroll
    for (int k = 0; k < 8; k++) acc[k] += __shfl_xor(acc[k], 8);
    wsum += __shfl_xor(wsum, 8);

    // self loop
    {
        float lg = als1[node_c * 2 + head] + ad;
        lg = (lg >= 0.f) ? lg : NEG_SLOPE * lg;
        float w = __expf(lg);
        float4 rv = h4[(size_t)node_c * 8 + i];
        const __half* hp = (const __half*)&rv;
#pragma unroll
        for (int k = 0; k < 8; k++)
            acc[k] = fmaf(w, __half2float(hp[k]), acc[k]);
        wsum += w;
    }

    float inv = 1.f / (wsum + 1e-16f);
    if (hlf == 0) {
        union { float4 f4; __half2 h2[4]; } u;
#pragma unroll
        for (int c4 = 0; c4 < 4; c4++) {
            float v0 = fmaxf(acc[2*c4]   * inv + b1[i * 8 + 2*c4],     0.f);
            float v1 = fmaxf(acc[2*c4+1] * inv + b1[i * 8 + 2*c4 + 1], 0.f);
            u.h2[c4] = __floats2half2_rn(v0, v1);
        }
        h2t[nl * 8 + i] = u.f4;
    }
    __syncthreads();

    // ---- fused h3 = h2 @ W2 : 4 waves, wave wv computes output cols wv*16..+15 ----
    int wv = t >> 6;
    int l15 = l & 15, quad = l >> 4;
    const _Float16* h2p = (const _Float16*)h2t;
    half8 a0 = *(const half8*)(h2p + l15 * 64 + quad * 8);
    half8 a1 = *(const half8*)(h2p + l15 * 64 + 32 + quad * 8);
    half8 bf0 = *(const half8*)(&w2t[wv * 16 + l15][quad * 8]);
    half8 bf1 = *(const half8*)(&w2t[wv * 16 + l15][32 + quad * 8]);
    float4v cacc = {0.f, 0.f, 0.f, 0.f};
    cacc = __builtin_amdgcn_mfma_f32_16x16x32_f16(a0, bf0, cacc, 0, 0, 0);
    cacc = __builtin_amdgcn_mfma_f32_16x16x32_f16(a1, bf1, cacc, 0, 0, 0);
#pragma unroll
    for (int r = 0; r < 4; r++)
        h3t[quad * 4 + r][wv * 16 + l15] = cacc[r];
    __syncthreads();

    // epilogue: h3 store (fp16) + attention logits for layer 2
    int m = t >> 4, part = t & 15;
    int g = blockIdx.x * 16 + m;
    float ps = 0.f, pd = 0.f;
    union { float2 f2; _Float16 h[4]; } u2;
#pragma unroll
    for (int cc = 0; cc < 4; cc++) {
        float v = h3t[m][part * 4 + cc];
        ps += v * a_src2[part * 4 + cc];
        pd += v * a_dst2[part * 4 + cc];
        u2.h[cc] = (_Float16)v;
    }
    if (g < N)
        *(float2*)(h3h + (size_t)g * 64 + part * 4) = u2.f2;
    ps += __shfl_xor(ps, 1); ps += __shfl_xor(ps, 2);
    ps += __shfl_xor(ps, 4); ps += __shfl_xor(ps, 8);
    pd += __shfl_xor(pd, 1); pd += __shfl_xor(pd, 2);
    pd += __shfl_xor(pd, 4); pd += __shfl_xor(pd, 8);
    if (part == 0 && g < N) { als2[g] = ps; ald2[g] = pd; }
}

// ---------------- Gather layer 2: 16 lanes/node, 4 nodes/wave + LayerNorm ----------------
__global__ void k_gather2(const int* __restrict__ rs, const int* __restrict__ cur,
                          const int* __restrict__ ssrc, const float4* __restrict__ h4,
                          const float* __restrict__ als2, const float* __restrict__ ald2,
                          const float* __restrict__ b2, const float* __restrict__ gamma,
                          const float* __restrict__ beta, float* __restrict__ out, int N)
{
    int t = threadIdx.x;
    int l = t & 63;
    int q = l & 15;
    int i = q & 7;
    int hlf = q >> 3;
    int grpbase = l & 48;

    int node = blockIdx.x * 16 + (t >> 4);
    bool live = node < N;
    int node_c = live ? node : (N - 1);

    int beg = rs[node_c];
    int cnt = live ? (cur[node_c] - beg) : 0;
    float ad = ald2[node_c];

    int mc = cnt;
    mc = max(mc, __shfl_xor(mc, 16));
    mc = max(mc, __shfl_xor(mc, 32));

    float acc[8];
#pragma unroll
    for (int k = 0; k < 8; k++) acc[k] = 0.f;
    float wsum = 0.f;

    for (int b = 0; b < mc; b += 16) {
        int slot = b + q;
        bool valid = slot < cnt;
        int idx = valid ? (beg + slot) : 0;
        int s = ssrc[idx];
        if (!valid) s = node_c;
        float lg = als2[s] + ad;
        lg = (lg >= 0.f) ? lg : NEG_SLOPE * lg;
        float w = valid ? __expf(lg) : 0.f;

#pragma unroll
        for (int r = 0; r < 8; r++) {
            int srcl = grpbase + hlf * 8 + r;
            int sr = __shfl(s, srcl);
            float wr = __shfl(w, srcl);
            float4 rv = h4[(size_t)sr * 8 + i];
            const __half* hp = (const __half*)&rv;
#pragma unroll
            for (int k = 0; k < 8; k++)
                acc[k] = fmaf(wr, __half2float(hp[k]), acc[k]);
            wsum += wr;
        }
    }

#pragma unroll
    for (int k = 0; k < 8; k++) acc[k] += __shfl_xor(acc[k], 8);
    wsum += __shfl_xor(wsum, 8);

    // self loop
    {
        float lg = als2[node_c] + ad;
        lg = (lg >= 0.f) ? lg : NEG_SLOPE * lg;
        float w = __expf(lg);
        float4 rv = h4[(size_t)node_c * 8 + i];
        const __half* hp = (const __half*)&rv;
#pragma unroll
        for (int k = 0; k < 8; k++)
            acc[k] = fmaf(w, __half2float(hp[k]), acc[k]);
        wsum += w;
    }

    float inv = 1.f / (wsum + 1e-16f);
    float o[8];
    float s = 0.f;
#pragma unroll
    for (int k = 0; k < 8; k++) { o[k] = acc[k] * inv + b2[i * 8 + k]; s += o[k]; }
    s += __shfl_xor(s, 1); s += __shfl_xor(s, 2); s += __shfl_xor(s, 4);
    float mu = s * (1.f / 64.f);
    float v = 0.f;
#pragma unroll
    for (int k = 0; k < 8; k++) { float d = o[k] - mu; v += d * d; }
    v += __shfl_xor(v, 1); v += __shfl_xor(v, 2); v += __shfl_xor(v, 4);
    v *= (1.f / 64.f);
    float rstd = rsqrtf(v + 1e-5f);
    if (live && hlf == 0) {
        float res[8];
#pragma unroll
        for (int k = 0; k < 8; k++)
            res[k] = (o[k] - mu) * rstd * gamma[i * 8 + k] + beta[i * 8 + k];
        float4* op = (float4*)(out + (size_t)node * 64 + i * 8);
        op[0] = make_float4(res[0], res[1], res[2], res[3]);
        op[1] = make_float4(res[4], res[5], res[6], res[7]);
    }
}

extern "C" void kernel_launch(void* const* d_in, const int* in_sizes, int n_in,
                              void* d_out, int out_size, void* d_ws, size_t ws_size,
                              hipStream_t stream) {
    const float* x        = (const float*)d_in[0];
    const int*   ei       = (const int*)  d_in[1];
    const int*   type_ids = (const int*)  d_in[2];
    const float* type_emb = (const float*)d_in[3];
    const float* W1       = (const float*)d_in[4];
    const float* a_src1   = (const float*)d_in[5];
    const float* a_dst1   = (const float*)d_in[6];
    const float* b1       = (const float*)d_in[7];
    const float* W2       = (const float*)d_in[8];
    const float* a_src2   = (const float*)d_in[9];
    const float* a_dst2   = (const float*)d_in[10];
    const float* b2       = (const float*)d_in[11];
    const float* gamma    = (const float*)d_in[12];
    const float* beta     = (const float*)d_in[13];

    int N = in_sizes[0] / 5;
    int E = in_sizes[1] / 2;
    int NBKT = (N + BKT_NODES - 1) >> BKT_SHIFT;

    // Workspace: pk (16 MB, dead after k_build) overlaid on h3h (12.8 MB).
    char* base = (char*)d_ws;
    size_t off = 0;
    auto carve = [&](size_t bytes) { void* p = base + off; off += (bytes + 255) & ~(size_t)255; return p; };
    __half2* h1h = (__half2*)carve((size_t)N * 64 * sizeof(__half));
    size_t pk_bytes = (size_t)NBKT * BKT_CAP * sizeof(unsigned int);
    size_t h3_bytes = (size_t)N * 64 * sizeof(__half);
    char* uni = (char*)carve(pk_bytes > h3_bytes ? pk_bytes : h3_bytes);
    unsigned int* pk = (unsigned int*)uni;
    _Float16* h3h = (_Float16*)uni;
    float* als1  = (float*)carve((size_t)N * 2 * sizeof(float));
    float* ald1  = (float*)carve((size_t)N * 2 * sizeof(float));
    float* als2  = (float*)carve((size_t)N * sizeof(float));
    float* ald2  = (float*)carve((size_t)N * sizeof(float));
    int*   rs    = (int*)carve((size_t)N * sizeof(int));
    int*   cur   = (int*)carve((size_t)N * sizeof(int));
    int*   bcnt  = (int*)carve(1024 * sizeof(int));
    int*   ssrc  = (int*)carve((size_t)E * sizeof(int) + 256);

    dim3 tb(256);
    dim3 tb512(512);

    k_node1<<<dim3((N + 3) / 4), tb, 0, stream>>>(x, type_ids, type_emb, W1, a_src1, a_dst1,
                                                  h1h, als1, ald1, bcnt, N);

    k_bucketA<<<dim3((E + CHUNK - 1) / CHUNK), tb512, 0, stream>>>(ei, pk, bcnt, E, NBKT);
    k_build<<<dim3(NBKT), tb512, 0, stream>>>(pk, bcnt, rs, cur, ssrc, N);

    dim3 ng((N + 15) / 16);
    k_gather1m<<<ng, tb, 0, stream>>>(rs, cur, ssrc, (const float4*)h1h, als1, ald1, b1,
                                      W2, a_src2, a_dst2, h3h, als2, ald2, N);
    k_gather2<<<ng, tb, 0, stream>>>(rs, cur, ssrc, (const float4*)h3h, als2, ald2, b2,
                                     gamma, beta, (float*)d_out, N);
}